// Round 7
// baseline (269.954 us; speedup 1.0000x reference)
//
#include <hip/hip_runtime.h>

// DiagLRConv: out[n,o,h,w] = sum_{k,i} fw[o,i,k] * x[n,i,h+k-2,w+k-2]
// x: (16,16,512,512) fp32, fw: (16,16,5) fp32, out fp32.
//
// LDS-free MFMA formulation. Per 16x16 tile (16 px x 16 o at fixed h):
//   D(px,o) = sum_K X'(px,K) W'(o,K),  K=(tap,i) 80->96 pad, 3x 16x16x32 bf16.
// A=X' fragments are loaded DIRECTLY from global x (8 dwords per lane off 8
// SGPR channel bases, 64B-coalesced per quarter), converted in-register with
// v_cvt_pk_bf16_f32. Zero-padding = clamped address + AND mask; tap-5 pad
// column is annihilated by the zeroed B=W fragment (verified R5/R6 mappings).

#define HH    512
#define WW    512
#define CH    16
#define KK    5
#define IMG   (HH * WW)
#define CHIMG (CH * IMG)

typedef __attribute__((ext_vector_type(8))) short bf16x8;
typedef __attribute__((ext_vector_type(4))) float f32x4;
typedef __attribute__((ext_vector_type(4))) int   i32x4;

union I4S8 { i32x4 i; bf16x8 s; };

__device__ __forceinline__ unsigned cvt_pk_bf16(float lo, float hi) {
    unsigned r;
    asm("v_cvt_pk_bf16_f32 %0, %1, %2" : "=v"(r) : "v"(lo), "v"(hi));
    return r;
}

// Load one tile's A-operand raw floats + validity masks. 24 loads, all using
// SGPR bases cb0..cb7 with a shared per-lane 32-bit dword offset.
#define LOADT(F, M, G)                                                         \
    {                                                                          \
        _Pragma("unroll")                                                      \
        for (int s = 0; s < 3; ++s) {                                          \
            const int wun = (G) * 16 + pxt[s];                                 \
            const bool vw = (unsigned)wun < (unsigned)WW;                      \
            const int wcl = wun < 0 ? 0 : (wun > WW - 1 ? WW - 1 : wun);       \
            const unsigned off = vbase[s] + (unsigned)wcl;                     \
            M[s] = vw ? vhm[s] : 0;                                            \
            F[s][0] = cb0[off]; F[s][1] = cb1[off];                            \
            F[s][2] = cb2[off]; F[s][3] = cb3[off];                            \
            F[s][4] = cb4[off]; F[s][5] = cb5[off];                            \
            F[s][6] = cb6[off]; F[s][7] = cb7[off];                            \
        }                                                                      \
    }

// Convert+mask+MFMA+store for one tile.
#define CONSUME(F, M, G)                                                       \
    {                                                                          \
        f32x4 acc = (f32x4){0.f, 0.f, 0.f, 0.f};                               \
        _Pragma("unroll")                                                      \
        for (int s = 0; s < 3; ++s) {                                          \
            I4S8 b;                                                            \
            b.i.x = (int)cvt_pk_bf16(F[s][0], F[s][1]) & M[s];                 \
            b.i.y = (int)cvt_pk_bf16(F[s][2], F[s][3]) & M[s];                 \
            b.i.z = (int)cvt_pk_bf16(F[s][4], F[s][5]) & M[s];                 \
            b.i.w = (int)cvt_pk_bf16(F[s][6], F[s][7]) & M[s];                 \
            acc = __builtin_amdgcn_mfma_f32_16x16x32_bf16(                     \
                b.s, wfrag[s], acc, 0, 0, 0);                                  \
        }                                                                      \
        *(f32x4*)(outn + sbase + (G) * 16) = acc;                              \
    }

// NOTE (R2): never cap VGPRs via __launch_bounds__ min-waves — acc spills.
__global__ __launch_bounds__(256)
void diag_conv_direct(const float* __restrict__ x,
                      const float* __restrict__ fw,
                      float* __restrict__ out)
{
    const int tid = threadIdx.x;
    const int bid = blockIdx.x;

    // 1024 blocks = 8 XCDs x 128 contiguous (2 images each). Bijective.
    const int swz = ((bid & 7) << 7) | (bid >> 3);
    const int n  = swz >> 6;        // 0..15
    const int hb = swz & 63;        // 0..63, 8 h-rows per block

    const int wv   = tid >> 6;      // wave 0..3: 2 h-rows each
    const int lane = tid & 63;
    const int px  = lane & 15;
    const int ihl = (lane >> 4) & 1;
    const int tb  = lane >> 5;

    // ---- B fragments (weights): n=o=lane&15, K-slot=(lane>>4)*8+j ----------
    // tap = 2s + tb, i = ihl*8 + j.  tap==5 (s=2, tb=1) -> zero. (verified R6)
    bf16x8 wfrag[3];
#pragma unroll
    for (int s = 0; s < 3; ++s) {
        const int tap = 2 * s + tb;
        I4S8 a;
        a.i = (i32x4){0, 0, 0, 0};
        if (tap < KK) {
            const float* __restrict__ wp = fw + ((size_t)px * CH + ihl * 8) * KK + tap;
            a.i.x = (int)cvt_pk_bf16(wp[0 * KK], wp[1 * KK]);
            a.i.y = (int)cvt_pk_bf16(wp[2 * KK], wp[3 * KK]);
            a.i.z = (int)cvt_pk_bf16(wp[4 * KK], wp[5 * KK]);
            a.i.w = (int)cvt_pk_bf16(wp[6 * KK], wp[7 * KK]);
        }
        wfrag[s] = a.s;
    }

    // SGPR channel bases: channel i = ihl*8 + j  ->  base cb_j + (ihl*8*IMG in voffset)
    const float* __restrict__ xn = x + (size_t)n * CHIMG;
    float* __restrict__ outn     = out + (size_t)n * CHIMG;
    const float* __restrict__ cb0 = xn + 0 * (size_t)IMG;
    const float* __restrict__ cb1 = xn + 1 * (size_t)IMG;
    const float* __restrict__ cb2 = xn + 2 * (size_t)IMG;
    const float* __restrict__ cb3 = xn + 3 * (size_t)IMG;
    const float* __restrict__ cb4 = xn + 4 * (size_t)IMG;
    const float* __restrict__ cb5 = xn + 5 * (size_t)IMG;
    const float* __restrict__ cb6 = xn + 6 * (size_t)IMG;
    const float* __restrict__ cb7 = xn + 7 * (size_t)IMG;

    // per-lane w-term (g-independent): px + tap - 2
    int pxt[3];
#pragma unroll
    for (int s = 0; s < 3; ++s) pxt[s] = px + 2 * s + tb - 2;

#pragma unroll 1
    for (int h2 = 0; h2 < 2; ++h2) {
        const int h = hb * 8 + wv * 2 + h2;

        // per-s per-lane row base (clamped) + row-validity mask
        unsigned vbase[3];
        int vhm[3];
#pragma unroll
        for (int s = 0; s < 3; ++s) {
            const int r  = h + 2 * s + tb - 2;
            const bool vh = (unsigned)r < (unsigned)HH;
            const int rc = r < 0 ? 0 : (r > HH - 1 ? HH - 1 : r);
            vbase[s] = (unsigned)(ihl * 8 * IMG + rc * WW);
            vhm[s]   = vh ? -1 : 0;
        }
        // store base (dword index into outn): o=lane&15, px-quad=(lane>>4)*4
        const unsigned sbase = (unsigned)(px * IMG + h * WW + ((lane >> 4) << 2));

        // ---- 2-deep tile pipeline over g = 0..31 ----
        float F0[3][8], F1[3][8];
        int   M0[3], M1[3];
        LOADT(F0, M0, 0);
#pragma unroll 1
        for (int g = 0; g < 32; g += 2) {
            LOADT(F1, M1, g + 1);
            CONSUME(F0, M0, g);
            const int g2 = (g + 2 < 32) ? g + 2 : 31;   // last prefetch redundant
            LOADT(F0, M0, g2);
            CONSUME(F1, M1, g + 1);
        }
    }
}

extern "C" void kernel_launch(void* const* d_in, const int* in_sizes, int n_in,
                              void* d_out, int out_size, void* d_ws, size_t ws_size,
                              hipStream_t stream)
{
    const float* x  = (const float*)d_in[0];
    const float* fw = (const float*)d_in[1];
    float* out      = (float*)d_out;

    // 1024 blocks = 16 n x 64 hb ; 4 blocks/CU exactly.
    diag_conv_direct<<<dim3(1024), dim3(256), 0, stream>>>(x, fw, out);
}